// Round 3
// baseline (682.024 us; speedup 1.0000x reference)
//
#include <hip/hip_runtime.h>
#include <math.h>

typedef __bf16 bf16;
typedef __attribute__((ext_vector_type(8))) __bf16 bf16x8;
typedef __attribute__((ext_vector_type(4))) float floatx4;

#define DIM 512
#define DFF 2048
#define SEQ 4096
#define ROWS 32768            // 8 * 4096

#define GLOBAL_AS(p) ((const __attribute__((address_space(1))) void*)(p))
#define LDS_AS(p)    ((__attribute__((address_space(3))) void*)(p))

// ---------------- weight prep: fp32 [K][N] -> bf16 [N][K] (transposed) ----------------
__global__ __launch_bounds__(256) void prep_w_kernel(const float* __restrict__ W,
                                                     bf16* __restrict__ Wt, int K, int N)
{
    int idx = blockIdx.x * 256 + threadIdx.x;
    if (idx >= K * N) return;
    int k = idx % K;
    int n = idx / K;
    Wt[idx] = (bf16)W[(size_t)k * N + n];
}

// three 512x512 weights (q,k,v) in one launch, grid 3072
__global__ __launch_bounds__(256) void prep_w3_kernel(const float* __restrict__ Wq,
                                                      const float* __restrict__ Wk,
                                                      const float* __restrict__ Wv,
                                                      bf16* __restrict__ Wt)
{
    int idx = blockIdx.x * 256 + threadIdx.x;          // 0 .. 3*512*512
    int which = idx >> 18;                             // /(512*512)
    int r = idx & 262143;
    int k = r & 511;
    int n = r >> 9;
    const float* W = (which == 0) ? Wq : (which == 1 ? Wk : Wv);
    Wt[idx] = (bf16)W[(size_t)k * 512 + n];
}

__global__ __launch_bounds__(256) void pack_bias_kernel(const float* __restrict__ bq,
                                                        const float* __restrict__ bk,
                                                        const float* __restrict__ bv,
                                                        float* __restrict__ out)
{
    int i = blockIdx.x * 256 + threadIdx.x;
    if (i >= 1536) return;
    out[i] = (i < 512) ? bq[i] : (i < 1024 ? bk[i - 512] : bv[i - 1024]);
}

// ---------------- wave reduction ----------------
__device__ inline float wave_red(float v)
{
#pragma unroll
    for (int off = 32; off; off >>= 1) v += __shfl_xor(v, off, 64);
    return v;
}

// ---------------- fused series-decomposition + LayerNorm1 ----------------
__global__ __launch_bounds__(256) void decomp_ln_kernel(const float* __restrict__ x,
                                                        const float* __restrict__ g,
                                                        const float* __restrict__ be,
                                                        float* __restrict__ S,
                                                        bf16* __restrict__ XN)
{
    int wave = threadIdx.x >> 6, lane = threadIdx.x & 63;
    int r = blockIdx.x * 4 + wave;
    int n = r & (SEQ - 1);
    const float4* xr = (const float4*)(x + (size_t)r * DIM);
    float4 z = make_float4(0.f, 0.f, 0.f, 0.f);
    float s[8];
#pragma unroll
    for (int i = 0; i < 2; ++i) {
        int c4 = lane * 2 + i;
        float4 v0 = xr[c4];
        float4 vm = (n > 0)       ? xr[c4 - DIM / 4] : z;
        float4 vp = (n < SEQ - 1) ? xr[c4 + DIM / 4] : z;
        s[i * 4 + 0] = v0.x - (vm.x + v0.x + vp.x) * (1.f / 3.f);
        s[i * 4 + 1] = v0.y - (vm.y + v0.y + vp.y) * (1.f / 3.f);
        s[i * 4 + 2] = v0.z - (vm.z + v0.z + vp.z) * (1.f / 3.f);
        s[i * 4 + 3] = v0.w - (vm.w + v0.w + vp.w) * (1.f / 3.f);
    }
    float4* Sr = (float4*)(S + (size_t)r * DIM);
    Sr[lane * 2]     = make_float4(s[0], s[1], s[2], s[3]);
    Sr[lane * 2 + 1] = make_float4(s[4], s[5], s[6], s[7]);

    float sum = 0.f;
#pragma unroll
    for (int j = 0; j < 8; ++j) sum += s[j];
    sum = wave_red(sum);
    float mean = sum * (1.f / DIM);
    float vs = 0.f;
#pragma unroll
    for (int j = 0; j < 8; ++j) { float d = s[j] - mean; vs += d * d; }
    vs = wave_red(vs);
    float rstd = rsqrtf(vs * (1.f / DIM) + 1e-5f);

    int c = lane * 8;
    float4 g0 = ((const float4*)(g + c))[0],  g1v = ((const float4*)(g + c))[1];
    float4 b0 = ((const float4*)(be + c))[0], b1v = ((const float4*)(be + c))[1];
    bf16x8 o;
    o[0] = (bf16)((s[0] - mean) * rstd * g0.x + b0.x);
    o[1] = (bf16)((s[1] - mean) * rstd * g0.y + b0.y);
    o[2] = (bf16)((s[2] - mean) * rstd * g0.z + b0.z);
    o[3] = (bf16)((s[3] - mean) * rstd * g0.w + b0.w);
    o[4] = (bf16)((s[4] - mean) * rstd * g1v.x + b1v.x);
    o[5] = (bf16)((s[5] - mean) * rstd * g1v.y + b1v.y);
    o[6] = (bf16)((s[6] - mean) * rstd * g1v.z + b1v.z);
    o[7] = (bf16)((s[7] - mean) * rstd * g1v.w + b1v.w);
    *(bf16x8*)(XN + (size_t)r * DIM + c) = o;
}

// ---------------- plain LayerNorm (fp32 in -> bf16 out) ----------------
__global__ __launch_bounds__(256) void ln_kernel(const float* __restrict__ X,
                                                 const float* __restrict__ g,
                                                 const float* __restrict__ be,
                                                 bf16* __restrict__ XN)
{
    int wave = threadIdx.x >> 6, lane = threadIdx.x & 63;
    int r = blockIdx.x * 4 + wave;
    const float4* xr = (const float4*)(X + (size_t)r * DIM);
    float4 a0 = xr[lane * 2], a1 = xr[lane * 2 + 1];
    float s[8] = {a0.x, a0.y, a0.z, a0.w, a1.x, a1.y, a1.z, a1.w};
    float sum = 0.f;
#pragma unroll
    for (int j = 0; j < 8; ++j) sum += s[j];
    sum = wave_red(sum);
    float mean = sum * (1.f / DIM);
    float vs = 0.f;
#pragma unroll
    for (int j = 0; j < 8; ++j) { float d = s[j] - mean; vs += d * d; }
    vs = wave_red(vs);
    float rstd = rsqrtf(vs * (1.f / DIM) + 1e-5f);
    int c = lane * 8;
    float4 g0 = ((const float4*)(g + c))[0],  g1v = ((const float4*)(g + c))[1];
    float4 b0 = ((const float4*)(be + c))[0], b1v = ((const float4*)(be + c))[1];
    bf16x8 o;
    o[0] = (bf16)((s[0] - mean) * rstd * g0.x + b0.x);
    o[1] = (bf16)((s[1] - mean) * rstd * g0.y + b0.y);
    o[2] = (bf16)((s[2] - mean) * rstd * g0.z + b0.z);
    o[3] = (bf16)((s[3] - mean) * rstd * g0.w + b0.w);
    o[4] = (bf16)((s[4] - mean) * rstd * g1v.x + b1v.x);
    o[5] = (bf16)((s[5] - mean) * rstd * g1v.y + b1v.y);
    o[6] = (bf16)((s[6] - mean) * rstd * g1v.z + b1v.z);
    o[7] = (bf16)((s[7] - mean) * rstd * g1v.w + b1v.w);
    *(bf16x8*)(XN + (size_t)r * DIM + c) = o;
}

// ---------------- MFMA GEMM: C = A[M,K](bf16) @ Bt[N,K]^T(bf16) + bias, epilogues ----------------
// K-loop: triple-buffered, depth-2 prefetch with COUNTED vmcnt (T4). Each phase:
//   issue stage(i+2) -> ds_read+MFMA on buf[i] -> s_waitcnt vmcnt(4) (= stage(i+1)
//   landed, stage(i+2) still in flight) -> s_barrier.
// LDS tiles are chunk-swizzled: global source column q is XOR'd with (row&3) so the
// linear global_load_lds write leaves chunk (row, q) holding global (row, q^(row&3));
// ds_read applies the same XOR (rule 21: both-sides-or-neither). 8-way -> 4-way.
enum { M_QKV = 0, M_ATTN = 1, M_FFN1 = 2, M_FFN2 = 3 };

template <int MODE>
__global__ __launch_bounds__(256) void gemm_bt_kernel(const bf16* __restrict__ A, int lda,
                                                      const bf16* __restrict__ Bt,
                                                      const float* __restrict__ bias,
                                                      float* S, const float* __restrict__ X,
                                                      void* Cout, int ldc,
                                                      int N, int K, int rows_per_batch,
                                                      int m_off)
{
    __shared__ __align__(16) bf16 lA[3][128 * 32];   // 48 KB total -> 3 blocks/CU
    __shared__ __align__(16) bf16 lB[3][128 * 32];
    int tid = threadIdx.x;

    // T1 XCD-chunked swizzle (all grids %8==0 -> bijective)
    int nwg = gridDim.x * gridDim.y;
    int orig = blockIdx.y * gridDim.x + blockIdx.x;
    int wg = (orig & 7) * (nwg >> 3) + (orig >> 3);
    int m0 = (wg / gridDim.x) * 128;
    int n0 = (wg % gridDim.x) * 128;

    const bf16* Abase = A + (size_t)m0 * lda;
    const bf16* Bbase = Bt + (size_t)n0 * K;
    if (rows_per_batch) Bbase += (size_t)(m0 / rows_per_batch) * (size_t)N * K;

    int lane = tid & 63;
    int wave = tid >> 6;
    int wm = (wave >> 1) * 64;
    int wn = (wave & 1) * 64;
    int lm = lane & 15;
    int quad = lane >> 4;
    int i0w = tid & 192;

    floatx4 acc[4][4];
#pragma unroll
    for (int i = 0; i < 4; ++i)
#pragma unroll
        for (int j = 0; j < 4; ++j) acc[i][j] = (floatx4){0.f, 0.f, 0.f, 0.f};

    auto stage = [&](int buf, int k0) {
#pragma unroll
        for (int it = 0; it < 2; ++it) {
            int ib = it * 256 + i0w;
            int i  = ib + lane;
            int row = i >> 2;
            int col = ((i & 3) ^ (row & 3)) * 8;     // pre-swizzled source chunk
            __builtin_amdgcn_global_load_lds(GLOBAL_AS(Abase + (size_t)row * lda + k0 + col),
                                             LDS_AS(&lA[buf][ib * 8]), 16, 0, 0);
            __builtin_amdgcn_global_load_lds(GLOBAL_AS(Bbase + (size_t)row * K + k0 + col),
                                             LDS_AS(&lB[buf][ib * 8]), 16, 0, 0);
        }
    };

    // prologue: two stages in flight, wait for stage 0 only (vmcnt counts wave-level
    // vmem ops; 4 per stage per wave)
    stage(0, 0);
    stage(1, 32);
    asm volatile("s_waitcnt vmcnt(4)" ::: "memory");
    __builtin_amdgcn_s_barrier();

    int nsteps = K >> 5;
    int cur = 0;
    for (int s = 0; s < nsteps; ++s) {
        int kpre = (s + 2) << 5;
        bool issued = kpre < K;
        if (issued) {
            int nxt = cur + 2; if (nxt >= 3) nxt -= 3;
            stage(nxt, kpre);                       // depth-2 prefetch
        }

        bf16x8 af[4], bfv[4];
#pragma unroll
        for (int i = 0; i < 4; ++i) {
            int ra = wm + i * 16 + lm;
            af[i] = *(const bf16x8*)&lA[cur][ra * 32 + (quad ^ (ra & 3)) * 8];
        }
#pragma unroll
        for (int j = 0; j < 4; ++j) {
            int rb = wn + j * 16 + lm;
            bfv[j] = *(const bf16x8*)&lB[cur][rb * 32 + (quad ^ (rb & 3)) * 8];
        }
#pragma unroll
        for (int i = 0; i < 4; ++i)
#pragma unroll
            for (int j = 0; j < 4; ++j)
                acc[i][j] = __builtin_amdgcn_mfma_f32_16x16x32_bf16(af[i], bfv[j], acc[i][j], 0, 0, 0);

        // counted wait: next phase's buffer (stage s+1) complete; stage s+2 in flight
        if (issued) asm volatile("s_waitcnt vmcnt(4)" ::: "memory");
        else        asm volatile("s_waitcnt vmcnt(0)" ::: "memory");
        __builtin_amdgcn_s_barrier();
        cur = (cur == 2) ? 0 : cur + 1;
    }

    // epilogue: C/D layout col = lane&15, row = quad*4 + e (m89-verified)
#pragma unroll
    for (int i = 0; i < 4; ++i) {
        int gm_base = m0 + wm + i * 16 + quad * 4;
#pragma unroll
        for (int j = 0; j < 4; ++j) {
            int gn = n0 + wn + j * 16 + lm;
            float bia = bias[gn];
#pragma unroll
            for (int e = 0; e < 4; ++e) {
                int gm = gm_base + e;
                float val = acc[i][j][e] + bia;
                if constexpr (MODE == M_QKV) {
                    if (gn < 1024) val = (val > 0.f) ? val + 1.f : __expf(val);  // elu+1 on q,k
                    ((bf16*)Cout)[(size_t)gm * ldc + gn] = (bf16)val;
                } else if constexpr (MODE == M_ATTN) {
                    S[(size_t)gm * DIM + gn] += val;          // seasonal += attn + bo
                } else if constexpr (MODE == M_FFN1) {
                    val = 0.5f * val * (1.f + erff(val * 0.70710678118654752f));  // exact gelu
                    ((bf16*)Cout)[(size_t)gm * ldc + gn] = (bf16)val;
                } else {  // M_FFN2: out = ffn2 + seasonal(out) + trend(x), fused final
                    int gmg = m_off + gm;
                    int nn = gmg & (SEQ - 1);
                    size_t o = (size_t)gmg * DIM + gn;
                    float xc = X[o];
                    float xm = (nn > 0)       ? X[o - DIM] : 0.f;
                    float xp = (nn < SEQ - 1) ? X[o + DIM] : 0.f;
                    float* op = (float*)Cout;
                    op[o] = val + op[o] + (xm + xc + xp) * (1.f / 3.f);
                }
            }
        }
    }
}

// ---------------- kv einsum via MFMA: KV[kc][b*8+h][d][f] = sum_{n in kc-chunk} k[n][d]*v[n][f] ----
// One block per (kc,h,b); 256 blocks = 1 block/CU, so depth-2 counted-vmcnt prefetch
// is the only latency hiding available. 8 vmem ops per stage per wave.
__global__ __launch_bounds__(256) void kv_mfma_kernel(const bf16* __restrict__ QKV,
                                                      float* __restrict__ KV)
{
    int kc = blockIdx.x, h = blockIdx.y, b = blockIdx.z;
    __shared__ __align__(16) bf16 lbuf[3][2 * 128 * 64];   // (lk | lv) x 3, 96 KB
    int tid = threadIdx.x;
    int lane = tid & 63, wave = tid >> 6;
    int lm = lane & 15, quad = lane >> 4;

    floatx4 acc[4][4];
#pragma unroll
    for (int i = 0; i < 4; ++i)
#pragma unroll
        for (int j = 0; j < 4; ++j) acc[i][j] = (floatx4){0.f, 0.f, 0.f, 0.f};

    const bf16* kb = QKV + (size_t)b * SEQ * 1536 + 512 + (size_t)h * 64;
    const bf16* vb = kb + 512;
    int drow = lane >> 3;          // row-within-instruction (8 rows x 128 B = 1 KB)
    int d0 = (lane & 7) * 8;

    auto stage = [&](int buf, int it) {
        int n0 = kc * 1024 + it * 128;
#pragma unroll
        for (int q = 0; q < 4; ++q) {
            int nbase = wave * 32 + q * 8;              // wave-uniform
            int ldsoff = wave * 2048 + q * 512;         // elements (x2B = bytes/2)
            __builtin_amdgcn_global_load_lds(GLOBAL_AS(kb + (size_t)(n0 + nbase + drow) * 1536 + d0),
                                             LDS_AS(&lbuf[buf][ldsoff]), 16, 0, 0);
            __builtin_amdgcn_global_load_lds(GLOBAL_AS(vb + (size_t)(n0 + nbase + drow) * 1536 + d0),
                                             LDS_AS(&lbuf[buf][8192 + ldsoff]), 16, 0, 0);
        }
    };

    stage(0, 0);
    stage(1, 1);
    asm volatile("s_waitcnt vmcnt(8)" ::: "memory");   // stage 0 landed
    __builtin_amdgcn_s_barrier();

    int cur = 0;
    for (int it = 0; it < 8; ++it) {
        bool issued = (it + 2) < 8;
        if (issued) {
            int nxt = cur + 2; if (nxt >= 3) nxt -= 3;
            stage(nxt, it + 2);
        }
        const bf16* lk = lbuf[cur];
        const bf16* lv = lbuf[cur] + 8192;

        int nw = wave * 32 + quad * 8;
        bf16x8 af[4], bfv[4];
#pragma unroll
        for (int i = 0; i < 4; ++i) {
            int dd = i * 16 + lm;
#pragma unroll
            for (int j = 0; j < 8; ++j) af[i][j] = lk[(nw + j) * 64 + dd];
#pragma unroll
            for (int j = 0; j < 8; ++j) bfv[i][j] = lv[(nw + j) * 64 + dd];
        }
#pragma unroll
        for (int i = 0; i < 4; ++i)
#pragma unroll
            for (int j = 0; j < 4; ++j)
                acc[i][j] = __builtin_amdgcn_mfma_f32_16x16x32_bf16(af[i], bfv[j], acc[i][j], 0, 0, 0);

        if (issued) asm volatile("s_waitcnt vmcnt(8)" ::: "memory");
        else        asm volatile("s_waitcnt vmcnt(0)" ::: "memory");
        __builtin_amdgcn_s_barrier();
        cur = (cur == 2) ? 0 : cur + 1;
    }

    // cross-wave reduce in LDS (reuse lbuf as 2 x 16 KB fp32), then store KV partial
    __syncthreads();
    float* red = (float*)lbuf;
    if (wave < 2) {
#pragma unroll
        for (int i = 0; i < 4; ++i)
#pragma unroll
            for (int j = 0; j < 4; ++j)
#pragma unroll
                for (int e = 0; e < 4; ++e)
                    red[wave * 4096 + (i * 16 + quad * 4 + e) * 64 + j * 16 + lm] = acc[i][j][e];
    }
    __syncthreads();
    if (wave >= 2) {
#pragma unroll
        for (int i = 0; i < 4; ++i)
#pragma unroll
            for (int j = 0; j < 4; ++j)
#pragma unroll
                for (int e = 0; e < 4; ++e)
                    red[(wave - 2) * 4096 + (i * 16 + quad * 4 + e) * 64 + j * 16 + lm] += acc[i][j][e];
    }
    __syncthreads();
    float* dst = KV + ((size_t)kc * 64 + b * 8 + h) * 4096;
#pragma unroll
    for (int p = 0; p < 4; ++p) {
        int e4 = (tid + p * 256) * 4;
        float4 a = *(const float4*)&red[e4];
        float4 c4 = *(const float4*)&red[4096 + e4];
        a.x += c4.x; a.y += c4.y; a.z += c4.z; a.w += c4.w;
        *(float4*)&dst[e4] = a;
    }
}

// ---------------- fold Wo (reduce 4 kc-partials): KVWT[b][j][h*64+d] ----------------
// 512 blocks = 64 (b,h) x 8 j-chunks; skv staged transposed so inner reads are b128 broadcasts.
__global__ __launch_bounds__(256) void kvw_kernel(const float* __restrict__ KV,
                                                  const float* __restrict__ Wo,
                                                  bf16* __restrict__ KVWT)
{
    int jc = blockIdx.x & 7, bh = blockIdx.x >> 3;
    int h = bh & 7, b = bh >> 3;
    __shared__ float skvT[64 * 68];   // [f][d], pad 4 keeps 16B align, 17.4 KB
    int tid = threadIdx.x;
    const float* src = KV + (size_t)bh * 4096;
#pragma unroll
    for (int p = 0; p < 16; ++p) {
        int e = tid + p * 256;
        float s = src[e] + src[e + 262144] + src[e + 524288] + src[e + 786432];
        skvT[(e & 63) * 68 + (e >> 6)] = s;     // transpose: skvT[f][d] = kv[d][f]
    }
    __syncthreads();

    int j = tid & 63, dq = tid >> 6;   // dq == wave index -> wave-uniform
    int j0 = jc * 64;
    floatx4 acc4[4];
#pragma unroll
    for (int c = 0; c < 4; ++c) acc4[c] = (floatx4){0.f, 0.f, 0.f, 0.f};
    const float* wop = Wo + (size_t)h * 64 * 512 + j0 + j;
#pragma unroll 8
    for (int f = 0; f < 64; ++f) {
        float w = wop[(size_t)f * 512];           // coalesced across lanes
        const float* sp = &skvT[f * 68 + dq * 16];
#pragma unroll
        for (int c = 0; c < 4; ++c) {
            floatx4 s = *(const floatx4*)(sp + c * 4);   // wave-uniform b128 broadcast
            acc4[c] += s * w;
        }
    }
    bf16* dst = KVWT + (size_t)b * 262144 + (size_t)(j0 + j) * 512 + h * 64 + dq * 16;
    bf16x8 o0, o1;
#pragma unroll
    for (int t = 0; t < 8; ++t) { o0[t] = (bf16)acc4[t >> 2][t & 3]; o1[t] = (bf16)acc4[2 + (t >> 2)][t & 3]; }
    *(bf16x8*)dst = o0;
    *(bf16x8*)(dst + 8) = o1;
}

// ---------------- launch ----------------
extern "C" void kernel_launch(void* const* d_in, const int* in_sizes, int n_in,
                              void* d_out, int out_size, void* d_ws, size_t ws_size,
                              hipStream_t stream)
{
    const float* x   = (const float*)d_in[0];
    const float* Wq  = (const float*)d_in[1];
    const float* bq  = (const float*)d_in[2];
    const float* Wk  = (const float*)d_in[3];
    const float* bk  = (const float*)d_in[4];
    const float* Wv  = (const float*)d_in[5];
    const float* bv  = (const float*)d_in[6];
    const float* Wo  = (const float*)d_in[7];
    const float* bo  = (const float*)d_in[8];
    const float* g1  = (const float*)d_in[9];
    const float* b1  = (const float*)d_in[10];
    const float* g2  = (const float*)d_in[11];
    const float* b2  = (const float*)d_in[12];
    const float* Wf1 = (const float*)d_in[13];
    const float* bf1 = (const float*)d_in[14];
    const float* Wf2 = (const float*)d_in[15];
    const float* bf2 = (const float*)d_in[16];
    float* out = (float*)d_out;      // also holds seasonal residual S (fp32)
    (void)in_sizes; (void)n_in; (void)out_size;

    char* ws = (char*)d_ws;
    size_t off = 0;
    auto alloc = [&](size_t bytes) -> char* {
        char* p = ws + off;
        off += (bytes + 255) & ~(size_t)255;
        return p;
    };
    bf16*  WqkvT = (bf16*)alloc((size_t)1536 * 512 * 2);
    float* bias3 = (float*)alloc(1536 * 4);
    bf16*  Wf1T  = (bf16*)alloc((size_t)2048 * 512 * 2);
    bf16*  Wf2T  = (bf16*)alloc((size_t)512 * 2048 * 2);
    size_t post_xn_off = 0;          // offset of first buffer dead by FFN time
    bf16*  XN    = (bf16*)alloc((size_t)ROWS * DIM * 2);
    post_xn_off = off;
    float* KV    = (float*)alloc((size_t)4 * 64 * 4096 * 4);  // 4 kc-partials
    bf16*  KVWT  = (bf16*)alloc((size_t)8 * 512 * 512 * 2);
    bf16*  QKV   = (bf16*)alloc((size_t)ROWS * 1536 * 2);

    // Merged-FFN path: full H1 [32768 x 2048] bf16 (134.2 MB) overlaid on
    // KV|KVWT|QKV (all dead once the ATTN gemm completed). Gate on ws_size.
    size_t h1_bytes  = (size_t)ROWS * DFF * 2;
    bool   merged    = ws_size >= post_xn_off + h1_bytes;
    bf16*  H1full    = (bf16*)(ws + post_xn_off);
    bf16*  H1chunk   = QKV;          // chunked fallback: aliases QKV (dead after attn)

    prep_w3_kernel<<<3072, 256, 0, stream>>>(Wq, Wk, Wv, WqkvT);
    prep_w_kernel<<<4096, 256, 0, stream>>>(Wf1, Wf1T, 512, 2048);
    prep_w_kernel<<<4096, 256, 0, stream>>>(Wf2, Wf2T, 2048, 512);
    pack_bias_kernel<<<6, 256, 0, stream>>>(bq, bk, bv, bias3);

    decomp_ln_kernel<<<8192, 256, 0, stream>>>(x, g1, b1, out, XN);

    gemm_bt_kernel<M_QKV><<<dim3(12, 256), 256, 0, stream>>>(
        XN, 512, WqkvT, bias3, nullptr, nullptr, QKV, 1536, 1536, 512, 0, 0);

    kv_mfma_kernel<<<dim3(4, 8, 8), 256, 0, stream>>>(QKV, KV);

    kvw_kernel<<<512, 256, 0, stream>>>(KV, Wo, KVWT);

    gemm_bt_kernel<M_ATTN><<<dim3(4, 256), 256, 0, stream>>>(
        QKV, 1536, KVWT, bo, out, nullptr, nullptr, 0, 512, 512, 4096, 0);

    ln_kernel<<<8192, 256, 0, stream>>>(out, g2, b2, XN);

    if (merged) {
        gemm_bt_kernel<M_FFN1><<<dim3(16, 256), 256, 0, stream>>>(
            XN, 512, Wf1T, bf1, nullptr, nullptr, H1full, 2048, 2048, 512, 0, 0);
        gemm_bt_kernel<M_FFN2><<<dim3(4, 256), 256, 0, stream>>>(
            H1full, 2048, Wf2T, bf2, nullptr, x, out, 512, 512, 2048, 0, 0);
    } else {
        for (int c = 0; c < 2; ++c) {
            gemm_bt_kernel<M_FFN1><<<dim3(16, 128), 256, 0, stream>>>(
                XN + (size_t)c * 16384 * 512, 512, Wf1T, bf1, nullptr, nullptr,
                H1chunk, 2048, 2048, 512, 0, 0);
            gemm_bt_kernel<M_FFN2><<<dim3(4, 128), 256, 0, stream>>>(
                H1chunk, 2048, Wf2T, bf2, nullptr, x, out, 512, 512, 2048, 0, c * 16384);
        }
    }
}

// Round 4
// 629.385 us; speedup vs baseline: 1.0836x; 1.0836x over previous
//
#include <hip/hip_runtime.h>
#include <math.h>

typedef __bf16 bf16;
typedef __attribute__((ext_vector_type(8))) __bf16 bf16x8;
typedef __attribute__((ext_vector_type(4))) float floatx4;

#define DIM 512
#define DFF 2048
#define SEQ 4096
#define ROWS 32768            // 8 * 4096

#define GLOBAL_AS(p) ((const __attribute__((address_space(1))) void*)(p))
#define LDS_AS(p)    ((__attribute__((address_space(3))) void*)(p))

// ---------------- weight prep: fp32 [K][N] -> bf16 [N][K] (transposed) ----------------
__global__ __launch_bounds__(256) void prep_w_kernel(const float* __restrict__ W,
                                                     bf16* __restrict__ Wt, int K, int N)
{
    int idx = blockIdx.x * 256 + threadIdx.x;
    if (idx >= K * N) return;
    int k = idx % K;
    int n = idx / K;
    Wt[idx] = (bf16)W[(size_t)k * N + n];
}

// three 512x512 weights (q,k,v) in one launch, grid 3072
__global__ __launch_bounds__(256) void prep_w3_kernel(const float* __restrict__ Wq,
                                                      const float* __restrict__ Wk,
                                                      const float* __restrict__ Wv,
                                                      bf16* __restrict__ Wt)
{
    int idx = blockIdx.x * 256 + threadIdx.x;          // 0 .. 3*512*512
    int which = idx >> 18;                             // /(512*512)
    int r = idx & 262143;
    int k = r & 511;
    int n = r >> 9;
    const float* W = (which == 0) ? Wq : (which == 1 ? Wk : Wv);
    Wt[idx] = (bf16)W[(size_t)k * 512 + n];
}

__global__ __launch_bounds__(256) void pack_bias_kernel(const float* __restrict__ bq,
                                                        const float* __restrict__ bk,
                                                        const float* __restrict__ bv,
                                                        float* __restrict__ out)
{
    int i = blockIdx.x * 256 + threadIdx.x;
    if (i >= 1536) return;
    out[i] = (i < 512) ? bq[i] : (i < 1024 ? bk[i - 512] : bv[i - 1024]);
}

// ---------------- wave reduction ----------------
__device__ inline float wave_red(float v)
{
#pragma unroll
    for (int off = 32; off; off >>= 1) v += __shfl_xor(v, off, 64);
    return v;
}

// ---------------- fused series-decomposition + LayerNorm1 ----------------
__global__ __launch_bounds__(256) void decomp_ln_kernel(const float* __restrict__ x,
                                                        const float* __restrict__ g,
                                                        const float* __restrict__ be,
                                                        float* __restrict__ S,
                                                        bf16* __restrict__ XN)
{
    int wave = threadIdx.x >> 6, lane = threadIdx.x & 63;
    int r = blockIdx.x * 4 + wave;
    int n = r & (SEQ - 1);
    const float4* xr = (const float4*)(x + (size_t)r * DIM);
    float4 z = make_float4(0.f, 0.f, 0.f, 0.f);
    float s[8];
#pragma unroll
    for (int i = 0; i < 2; ++i) {
        int c4 = lane * 2 + i;
        float4 v0 = xr[c4];
        float4 vm = (n > 0)       ? xr[c4 - DIM / 4] : z;
        float4 vp = (n < SEQ - 1) ? xr[c4 + DIM / 4] : z;
        s[i * 4 + 0] = v0.x - (vm.x + v0.x + vp.x) * (1.f / 3.f);
        s[i * 4 + 1] = v0.y - (vm.y + v0.y + vp.y) * (1.f / 3.f);
        s[i * 4 + 2] = v0.z - (vm.z + v0.z + vp.z) * (1.f / 3.f);
        s[i * 4 + 3] = v0.w - (vm.w + v0.w + vp.w) * (1.f / 3.f);
    }
    float4* Sr = (float4*)(S + (size_t)r * DIM);
    Sr[lane * 2]     = make_float4(s[0], s[1], s[2], s[3]);
    Sr[lane * 2 + 1] = make_float4(s[4], s[5], s[6], s[7]);

    float sum = 0.f;
#pragma unroll
    for (int j = 0; j < 8; ++j) sum += s[j];
    sum = wave_red(sum);
    float mean = sum * (1.f / DIM);
    float vs = 0.f;
#pragma unroll
    for (int j = 0; j < 8; ++j) { float d = s[j] - mean; vs += d * d; }
    vs = wave_red(vs);
    float rstd = rsqrtf(vs * (1.f / DIM) + 1e-5f);

    int c = lane * 8;
    float4 g0 = ((const float4*)(g + c))[0],  g1v = ((const float4*)(g + c))[1];
    float4 b0 = ((const float4*)(be + c))[0], b1v = ((const float4*)(be + c))[1];
    bf16x8 o;
    o[0] = (bf16)((s[0] - mean) * rstd * g0.x + b0.x);
    o[1] = (bf16)((s[1] - mean) * rstd * g0.y + b0.y);
    o[2] = (bf16)((s[2] - mean) * rstd * g0.z + b0.z);
    o[3] = (bf16)((s[3] - mean) * rstd * g0.w + b0.w);
    o[4] = (bf16)((s[4] - mean) * rstd * g1v.x + b1v.x);
    o[5] = (bf16)((s[5] - mean) * rstd * g1v.y + b1v.y);
    o[6] = (bf16)((s[6] - mean) * rstd * g1v.z + b1v.z);
    o[7] = (bf16)((s[7] - mean) * rstd * g1v.w + b1v.w);
    *(bf16x8*)(XN + (size_t)r * DIM + c) = o;
}

// ---------------- plain LayerNorm (fp32 in -> bf16 out) ----------------
__global__ __launch_bounds__(256) void ln_kernel(const float* __restrict__ X,
                                                 const float* __restrict__ g,
                                                 const float* __restrict__ be,
                                                 bf16* __restrict__ XN)
{
    int wave = threadIdx.x >> 6, lane = threadIdx.x & 63;
    int r = blockIdx.x * 4 + wave;
    const float4* xr = (const float4*)(X + (size_t)r * DIM);
    float4 a0 = xr[lane * 2], a1 = xr[lane * 2 + 1];
    float s[8] = {a0.x, a0.y, a0.z, a0.w, a1.x, a1.y, a1.z, a1.w};
    float sum = 0.f;
#pragma unroll
    for (int j = 0; j < 8; ++j) sum += s[j];
    sum = wave_red(sum);
    float mean = sum * (1.f / DIM);
    float vs = 0.f;
#pragma unroll
    for (int j = 0; j < 8; ++j) { float d = s[j] - mean; vs += d * d; }
    vs = wave_red(vs);
    float rstd = rsqrtf(vs * (1.f / DIM) + 1e-5f);
    int c = lane * 8;
    float4 g0 = ((const float4*)(g + c))[0],  g1v = ((const float4*)(g + c))[1];
    float4 b0 = ((const float4*)(be + c))[0], b1v = ((const float4*)(be + c))[1];
    bf16x8 o;
    o[0] = (bf16)((s[0] - mean) * rstd * g0.x + b0.x);
    o[1] = (bf16)((s[1] - mean) * rstd * g0.y + b0.y);
    o[2] = (bf16)((s[2] - mean) * rstd * g0.z + b0.z);
    o[3] = (bf16)((s[3] - mean) * rstd * g0.w + b0.w);
    o[4] = (bf16)((s[4] - mean) * rstd * g1v.x + b1v.x);
    o[5] = (bf16)((s[5] - mean) * rstd * g1v.y + b1v.y);
    o[6] = (bf16)((s[6] - mean) * rstd * g1v.z + b1v.z);
    o[7] = (bf16)((s[7] - mean) * rstd * g1v.w + b1v.w);
    *(bf16x8*)(XN + (size_t)r * DIM + c) = o;
}

// ---------------- MFMA GEMM: C = A[M,K](bf16) @ Bt[N,K]^T(bf16) + bias, epilogues ----------------
// K-loop: triple-buffered, depth-2 prefetch, counted vmcnt. CRITICAL ORDER (R3 lesson):
// ds_read(buf cur) comes BEFORE stage(buf nxt). global_load_lds is an LDS-writing VMEM
// op; if it precedes the typed LDS reads the compiler cannot disambiguate lA[cur] vs
// lA[nxt] and inserts s_waitcnt vmcnt(0) before the reads -- draining the prefetch
// queue and serializing the whole pipeline (R1-R3 all compiled to this). Reads-first
// needs at most an lgkmcnt wait before the gload_lds, which MFMA pays anyway.
enum { M_QKV = 0, M_ATTN = 1, M_FFN1 = 2, M_FFN2 = 3 };

template <int MODE>
__global__ __launch_bounds__(256) void gemm_bt_kernel(const bf16* __restrict__ A, int lda,
                                                      const bf16* __restrict__ Bt,
                                                      const float* __restrict__ bias,
                                                      float* S, const float* __restrict__ X,
                                                      void* Cout, int ldc,
                                                      int N, int K, int rows_per_batch,
                                                      int m_off)
{
    __shared__ __align__(16) bf16 lA[3][128 * 32];   // 48 KB total -> 3 blocks/CU
    __shared__ __align__(16) bf16 lB[3][128 * 32];
    int tid = threadIdx.x;

    // T1 XCD-chunked swizzle (all grids %8==0 -> bijective)
    int nwg = gridDim.x * gridDim.y;
    int orig = blockIdx.y * gridDim.x + blockIdx.x;
    int wg = (orig & 7) * (nwg >> 3) + (orig >> 3);
    int m0 = (wg / gridDim.x) * 128;
    int n0 = (wg % gridDim.x) * 128;

    const bf16* Abase = A + (size_t)m0 * lda;
    const bf16* Bbase = Bt + (size_t)n0 * K;
    if (rows_per_batch) Bbase += (size_t)(m0 / rows_per_batch) * (size_t)N * K;

    int lane = tid & 63;
    int wave = tid >> 6;
    int wm = (wave >> 1) * 64;
    int wn = (wave & 1) * 64;
    int lm = lane & 15;
    int quad = lane >> 4;
    int i0w = tid & 192;

    floatx4 acc[4][4];
#pragma unroll
    for (int i = 0; i < 4; ++i)
#pragma unroll
        for (int j = 0; j < 4; ++j) acc[i][j] = (floatx4){0.f, 0.f, 0.f, 0.f};

    auto stage = [&](int buf, int k0) {
#pragma unroll
        for (int it = 0; it < 2; ++it) {
            int ib = it * 256 + i0w;
            int i  = ib + lane;
            int row = i >> 2;
            int col = ((i & 3) ^ (row & 3)) * 8;     // pre-swizzled source chunk
            __builtin_amdgcn_global_load_lds(GLOBAL_AS(Abase + (size_t)row * lda + k0 + col),
                                             LDS_AS(&lA[buf][ib * 8]), 16, 0, 0);
            __builtin_amdgcn_global_load_lds(GLOBAL_AS(Bbase + (size_t)row * K + k0 + col),
                                             LDS_AS(&lB[buf][ib * 8]), 16, 0, 0);
        }
    };

    // prologue: two stages in flight, wait for stage 0 only (4 vmem ops per stage per wave)
    stage(0, 0);
    stage(1, 32);
    asm volatile("s_waitcnt vmcnt(4)" ::: "memory");
    __builtin_amdgcn_s_barrier();

    int nsteps = K >> 5;
    int cur = 0;
    for (int s = 0; s < nsteps; ++s) {
        // 1) LDS reads of the current buffer FIRST (see comment above)
        bf16x8 af[4], bfv[4];
#pragma unroll
        for (int i = 0; i < 4; ++i) {
            int ra = wm + i * 16 + lm;
            af[i] = *(const bf16x8*)&lA[cur][ra * 32 + (quad ^ (ra & 3)) * 8];
        }
#pragma unroll
        for (int j = 0; j < 4; ++j) {
            int rb = wn + j * 16 + lm;
            bfv[j] = *(const bf16x8*)&lB[cur][rb * 32 + (quad ^ (rb & 3)) * 8];
        }

        // 2) depth-2 prefetch issue (loads fly across the next barrier)
        int kpre = (s + 2) << 5;
        bool issued = kpre < K;
        if (issued) {
            int nxt = cur + 2; if (nxt >= 3) nxt -= 3;
            stage(nxt, kpre);
        }

        // 3) MFMA on the registers
#pragma unroll
        for (int i = 0; i < 4; ++i)
#pragma unroll
            for (int j = 0; j < 4; ++j)
                acc[i][j] = __builtin_amdgcn_mfma_f32_16x16x32_bf16(af[i], bfv[j], acc[i][j], 0, 0, 0);

        // 4) counted wait: stage s+1 landed; stage s+2 still in flight
        if (issued) asm volatile("s_waitcnt vmcnt(4)" ::: "memory");
        else        asm volatile("s_waitcnt vmcnt(0)" ::: "memory");
        __builtin_amdgcn_s_barrier();
        cur = (cur == 2) ? 0 : cur + 1;
    }

    // epilogue: C/D layout col = lane&15, row = quad*4 + e (m89-verified)
#pragma unroll
    for (int i = 0; i < 4; ++i) {
        int gm_base = m0 + wm + i * 16 + quad * 4;
#pragma unroll
        for (int j = 0; j < 4; ++j) {
            int gn = n0 + wn + j * 16 + lm;
            float bia = bias[gn];
            if constexpr (MODE == M_FFN2) {
                // out = ffn2 + seasonal(out) + trend(x); share the 6 X-rows across
                // the 4-row chunk (each interior row is read by up to 3 taps)
                int gmg0 = m_off + gm_base;
                int bn = gmg0 & (SEQ - 1);             // chunk base row, mult of 4
                size_t ob = (size_t)gmg0 * DIM + gn;
                const float* Xb = X + ob;
                float xr6[6];
#pragma unroll
                for (int r = 0; r < 6; ++r) {
                    int nr = bn + r - 1;
                    xr6[r] = (nr >= 0 && nr < SEQ) ? Xb[(long)(r - 1) * DIM] : 0.f;
                }
                float* op = (float*)Cout;
#pragma unroll
                for (int e = 0; e < 4; ++e) {
                    size_t o = ob + (size_t)e * DIM;
                    float val = acc[i][j][e] + bia;
                    op[o] = val + op[o] + (xr6[e] + xr6[e + 1] + xr6[e + 2]) * (1.f / 3.f);
                }
            } else {
#pragma unroll
                for (int e = 0; e < 4; ++e) {
                    int gm = gm_base + e;
                    float val = acc[i][j][e] + bia;
                    if constexpr (MODE == M_QKV) {
                        if (gn < 1024) val = (val > 0.f) ? val + 1.f : __expf(val);  // elu+1 on q,k
                        ((bf16*)Cout)[(size_t)gm * ldc + gn] = (bf16)val;
                    } else if constexpr (MODE == M_ATTN) {
                        S[(size_t)gm * DIM + gn] += val;          // seasonal += attn + bo
                    } else {  // M_FFN1
                        val = 0.5f * val * (1.f + erff(val * 0.70710678118654752f));  // exact gelu
                        ((bf16*)Cout)[(size_t)gm * ldc + gn] = (bf16)val;
                    }
                }
            }
        }
    }
}

// ---------------- kv einsum via MFMA: KV[kc][b*8+h][d][f] = sum_{n in kc-chunk} k[n][d]*v[n][f] ----
// One block per (kc,h,b); 256 blocks = 1 block/CU. Same reads-before-stage ordering.
__global__ __launch_bounds__(256) void kv_mfma_kernel(const bf16* __restrict__ QKV,
                                                      float* __restrict__ KV)
{
    int kc = blockIdx.x, h = blockIdx.y, b = blockIdx.z;
    __shared__ __align__(16) bf16 lbuf[3][2 * 128 * 64];   // (lk | lv) x 3, 96 KB
    int tid = threadIdx.x;
    int lane = tid & 63, wave = tid >> 6;
    int lm = lane & 15, quad = lane >> 4;

    floatx4 acc[4][4];
#pragma unroll
    for (int i = 0; i < 4; ++i)
#pragma unroll
        for (int j = 0; j < 4; ++j) acc[i][j] = (floatx4){0.f, 0.f, 0.f, 0.f};

    const bf16* kb = QKV + (size_t)b * SEQ * 1536 + 512 + (size_t)h * 64;
    const bf16* vb = kb + 512;
    int drow = lane >> 3;          // row-within-instruction (8 rows x 128 B = 1 KB)
    int d0 = (lane & 7) * 8;

    auto stage = [&](int buf, int it) {
        int n0 = kc * 1024 + it * 128;
#pragma unroll
        for (int q = 0; q < 4; ++q) {
            int nbase = wave * 32 + q * 8;              // wave-uniform
            int ldsoff = wave * 2048 + q * 512;         // elements (x2B = bytes/2)
            __builtin_amdgcn_global_load_lds(GLOBAL_AS(kb + (size_t)(n0 + nbase + drow) * 1536 + d0),
                                             LDS_AS(&lbuf[buf][ldsoff]), 16, 0, 0);
            __builtin_amdgcn_global_load_lds(GLOBAL_AS(vb + (size_t)(n0 + nbase + drow) * 1536 + d0),
                                             LDS_AS(&lbuf[buf][8192 + ldsoff]), 16, 0, 0);
        }
    };

    stage(0, 0);
    stage(1, 1);
    asm volatile("s_waitcnt vmcnt(8)" ::: "memory");   // stage 0 landed
    __builtin_amdgcn_s_barrier();

    int cur = 0;
    for (int it = 0; it < 8; ++it) {
        // 1) LDS reads first
        const bf16* lk = lbuf[cur];
        const bf16* lv = lbuf[cur] + 8192;
        int nw = wave * 32 + quad * 8;
        bf16x8 af[4], bfv[4];
#pragma unroll
        for (int i = 0; i < 4; ++i) {
            int dd = i * 16 + lm;
#pragma unroll
            for (int j = 0; j < 8; ++j) af[i][j] = lk[(nw + j) * 64 + dd];
#pragma unroll
            for (int j = 0; j < 8; ++j) bfv[i][j] = lv[(nw + j) * 64 + dd];
        }

        // 2) depth-2 prefetch
        bool issued = (it + 2) < 8;
        if (issued) {
            int nxt = cur + 2; if (nxt >= 3) nxt -= 3;
            stage(nxt, it + 2);
        }

        // 3) MFMA
#pragma unroll
        for (int i = 0; i < 4; ++i)
#pragma unroll
            for (int j = 0; j < 4; ++j)
                acc[i][j] = __builtin_amdgcn_mfma_f32_16x16x32_bf16(af[i], bfv[j], acc[i][j], 0, 0, 0);

        // 4) counted wait (8 vmem ops per stage per wave)
        if (issued) asm volatile("s_waitcnt vmcnt(8)" ::: "memory");
        else        asm volatile("s_waitcnt vmcnt(0)" ::: "memory");
        __builtin_amdgcn_s_barrier();
        cur = (cur == 2) ? 0 : cur + 1;
    }

    // cross-wave reduce in LDS (reuse lbuf as 2 x 16 KB fp32), then store KV partial
    __syncthreads();
    float* red = (float*)lbuf;
    if (wave < 2) {
#pragma unroll
        for (int i = 0; i < 4; ++i)
#pragma unroll
            for (int j = 0; j < 4; ++j)
#pragma unroll
                for (int e = 0; e < 4; ++e)
                    red[wave * 4096 + (i * 16 + quad * 4 + e) * 64 + j * 16 + lm] = acc[i][j][e];
    }
    __syncthreads();
    if (wave >= 2) {
#pragma unroll
        for (int i = 0; i < 4; ++i)
#pragma unroll
            for (int j = 0; j < 4; ++j)
#pragma unroll
                for (int e = 0; e < 4; ++e)
                    red[(wave - 2) * 4096 + (i * 16 + quad * 4 + e) * 64 + j * 16 + lm] += acc[i][j][e];
    }
    __syncthreads();
    float* dst = KV + ((size_t)kc * 64 + b * 8 + h) * 4096;
#pragma unroll
    for (int p = 0; p < 4; ++p) {
        int e4 = (tid + p * 256) * 4;
        float4 a = *(const float4*)&red[e4];
        float4 c4 = *(const float4*)&red[4096 + e4];
        a.x += c4.x; a.y += c4.y; a.z += c4.z; a.w += c4.w;
        *(float4*)&dst[e4] = a;
    }
}

// ---------------- fold Wo (reduce 4 kc-partials): KVWT[b][j][h*64+d] ----------------
// 512 blocks = 64 (b,h) x 8 j-chunks; skv staged transposed so inner reads are b128 broadcasts.
__global__ __launch_bounds__(256) void kvw_kernel(const float* __restrict__ KV,
                                                  const float* __restrict__ Wo,
                                                  bf16* __restrict__ KVWT)
{
    int jc = blockIdx.x & 7, bh = blockIdx.x >> 3;
    int h = bh & 7, b = bh >> 3;
    __shared__ float skvT[64 * 68];   // [f][d], pad 4 keeps 16B align, 17.4 KB
    int tid = threadIdx.x;
    const float* src = KV + (size_t)bh * 4096;
#pragma unroll
    for (int p = 0; p < 16; ++p) {
        int e = tid + p * 256;
        float s = src[e] + src[e + 262144] + src[e + 524288] + src[e + 786432];
        skvT[(e & 63) * 68 + (e >> 6)] = s;     // transpose: skvT[f][d] = kv[d][f]
    }
    __syncthreads();

    int j = tid & 63, dq = tid >> 6;   // dq == wave index -> wave-uniform
    int j0 = jc * 64;
    floatx4 acc4[4];
#pragma unroll
    for (int c = 0; c < 4; ++c) acc4[c] = (floatx4){0.f, 0.f, 0.f, 0.f};
    const float* wop = Wo + (size_t)h * 64 * 512 + j0 + j;
#pragma unroll 8
    for (int f = 0; f < 64; ++f) {
        float w = wop[(size_t)f * 512];           // coalesced across lanes
        const float* sp = &skvT[f * 68 + dq * 16];
#pragma unroll
        for (int c = 0; c < 4; ++c) {
            floatx4 s = *(const floatx4*)(sp + c * 4);   // wave-uniform b128 broadcast
            acc4[c] += s * w;
        }
    }
    bf16* dst = KVWT + (size_t)b * 262144 + (size_t)(j0 + j) * 512 + h * 64 + dq * 16;
    bf16x8 o0, o1;
#pragma unroll
    for (int t = 0; t < 8; ++t) { o0[t] = (bf16)acc4[t >> 2][t & 3]; o1[t] = (bf16)acc4[2 + (t >> 2)][t & 3]; }
    *(bf16x8*)dst = o0;
    *(bf16x8*)(dst + 8) = o1;
}

// ---------------- launch ----------------
extern "C" void kernel_launch(void* const* d_in, const int* in_sizes, int n_in,
                              void* d_out, int out_size, void* d_ws, size_t ws_size,
                              hipStream_t stream)
{
    const float* x   = (const float*)d_in[0];
    const float* Wq  = (const float*)d_in[1];
    const float* bq  = (const float*)d_in[2];
    const float* Wk  = (const float*)d_in[3];
    const float* bk  = (const float*)d_in[4];
    const float* Wv  = (const float*)d_in[5];
    const float* bv  = (const float*)d_in[6];
    const float* Wo  = (const float*)d_in[7];
    const float* bo  = (const float*)d_in[8];
    const float* g1  = (const float*)d_in[9];
    const float* b1  = (const float*)d_in[10];
    const float* g2  = (const float*)d_in[11];
    const float* b2  = (const float*)d_in[12];
    const float* Wf1 = (const float*)d_in[13];
    const float* bf1 = (const float*)d_in[14];
    const float* Wf2 = (const float*)d_in[15];
    const float* bf2 = (const float*)d_in[16];
    float* out = (float*)d_out;      // also holds seasonal residual S (fp32)
    (void)in_sizes; (void)n_in; (void)out_size;

    char* ws = (char*)d_ws;
    size_t off = 0;
    auto alloc = [&](size_t bytes) -> char* {
        char* p = ws + off;
        off += (bytes + 255) & ~(size_t)255;
        return p;
    };
    bf16*  WqkvT = (bf16*)alloc((size_t)1536 * 512 * 2);
    float* bias3 = (float*)alloc(1536 * 4);
    bf16*  Wf1T  = (bf16*)alloc((size_t)2048 * 512 * 2);
    bf16*  Wf2T  = (bf16*)alloc((size_t)512 * 2048 * 2);
    size_t post_xn_off = 0;          // offset of first buffer dead by FFN time
    bf16*  XN    = (bf16*)alloc((size_t)ROWS * DIM * 2);
    post_xn_off = off;
    float* KV    = (float*)alloc((size_t)4 * 64 * 4096 * 4);  // 4 kc-partials
    bf16*  KVWT  = (bf16*)alloc((size_t)8 * 512 * 512 * 2);
    bf16*  QKV   = (bf16*)alloc((size_t)ROWS * 1536 * 2);

    // Merged-FFN path: full H1 [32768 x 2048] bf16 (134.2 MB) overlaid on
    // KV|KVWT|QKV (all dead once the ATTN gemm completed). Gate on ws_size.
    size_t h1_bytes  = (size_t)ROWS * DFF * 2;
    bool   merged    = ws_size >= post_xn_off + h1_bytes;
    bf16*  H1full    = (bf16*)(ws + post_xn_off);
    bf16*  H1chunk   = QKV;          // chunked fallback: aliases QKV (dead after attn)

    prep_w3_kernel<<<3072, 256, 0, stream>>>(Wq, Wk, Wv, WqkvT);
    prep_w_kernel<<<4096, 256, 0, stream>>>(Wf1, Wf1T, 512, 2048);
    prep_w_kernel<<<4096, 256, 0, stream>>>(Wf2, Wf2T, 2048, 512);
    pack_bias_kernel<<<6, 256, 0, stream>>>(bq, bk, bv, bias3);

    decomp_ln_kernel<<<8192, 256, 0, stream>>>(x, g1, b1, out, XN);

    gemm_bt_kernel<M_QKV><<<dim3(12, 256), 256, 0, stream>>>(
        XN, 512, WqkvT, bias3, nullptr, nullptr, QKV, 1536, 1536, 512, 0, 0);

    kv_mfma_kernel<<<dim3(4, 8, 8), 256, 0, stream>>>(QKV, KV);

    kvw_kernel<<<512, 256, 0, stream>>>(KV, Wo, KVWT);

    gemm_bt_kernel<M_ATTN><<<dim3(4, 256), 256, 0, stream>>>(
        QKV, 1536, KVWT, bo, out, nullptr, nullptr, 0, 512, 512, 4096, 0);

    ln_kernel<<<8192, 256, 0, stream>>>(out, g2, b2, XN);

    if (merged) {
        gemm_bt_kernel<M_FFN1><<<dim3(16, 256), 256, 0, stream>>>(
            XN, 512, Wf1T, bf1, nullptr, nullptr, H1full, 2048, 2048, 512, 0, 0);
        gemm_bt_kernel<M_FFN2><<<dim3(4, 256), 256, 0, stream>>>(
            H1full, 2048, Wf2T, bf2, nullptr, x, out, 512, 512, 2048, 0, 0);
    } else {
        for (int c = 0; c < 2; ++c) {
            gemm_bt_kernel<M_FFN1><<<dim3(16, 128), 256, 0, stream>>>(
                XN + (size_t)c * 16384 * 512, 512, Wf1T, bf1, nullptr, nullptr,
                H1chunk, 2048, 2048, 512, 0, 0);
            gemm_bt_kernel<M_FFN2><<<dim3(4, 128), 256, 0, stream>>>(
                H1chunk, 2048, Wf2T, bf2, nullptr, x, out, 512, 512, 2048, 0, c * 16384);
        }
    }
}

// Round 5
// 616.688 us; speedup vs baseline: 1.1059x; 1.0206x over previous
//
#include <hip/hip_runtime.h>
#include <math.h>

typedef __bf16 bf16;
typedef __attribute__((ext_vector_type(8))) __bf16 bf16x8;
typedef __attribute__((ext_vector_type(4))) float floatx4;

#define DIM 512
#define DFF 2048
#define SEQ 4096
#define ROWS 32768            // 8 * 4096

#define GLOBAL_AS(p) ((const __attribute__((address_space(1))) void*)(p))
#define LDS_AS(p)    ((__attribute__((address_space(3))) void*)(p))

// ---------------- weight prep: fp32 [K][N] -> bf16 [N][K] (transposed) ----------------
__global__ __launch_bounds__(256) void prep_w_kernel(const float* __restrict__ W,
                                                     bf16* __restrict__ Wt, int K, int N)
{
    int idx = blockIdx.x * 256 + threadIdx.x;
    if (idx >= K * N) return;
    int k = idx % K;
    int n = idx / K;
    Wt[idx] = (bf16)W[(size_t)k * N + n];
}

// three 512x512 weights (q,k,v) in one launch, grid 3072
__global__ __launch_bounds__(256) void prep_w3_kernel(const float* __restrict__ Wq,
                                                      const float* __restrict__ Wk,
                                                      const float* __restrict__ Wv,
                                                      bf16* __restrict__ Wt)
{
    int idx = blockIdx.x * 256 + threadIdx.x;          // 0 .. 3*512*512
    int which = idx >> 18;                             // /(512*512)
    int r = idx & 262143;
    int k = r & 511;
    int n = r >> 9;
    const float* W = (which == 0) ? Wq : (which == 1 ? Wk : Wv);
    Wt[idx] = (bf16)W[(size_t)k * 512 + n];
}

__global__ __launch_bounds__(256) void pack_bias_kernel(const float* __restrict__ bq,
                                                        const float* __restrict__ bk,
                                                        const float* __restrict__ bv,
                                                        float* __restrict__ out)
{
    int i = blockIdx.x * 256 + threadIdx.x;
    if (i >= 1536) return;
    out[i] = (i < 512) ? bq[i] : (i < 1024 ? bk[i - 512] : bv[i - 1024]);
}

// ---------------- wave reduction ----------------
__device__ inline float wave_red(float v)
{
#pragma unroll
    for (int off = 32; off; off >>= 1) v += __shfl_xor(v, off, 64);
    return v;
}

// ---------------- fused series-decomposition + LayerNorm1 ----------------
__global__ __launch_bounds__(256) void decomp_ln_kernel(const float* __restrict__ x,
                                                        const float* __restrict__ g,
                                                        const float* __restrict__ be,
                                                        float* __restrict__ S,
                                                        bf16* __restrict__ XN)
{
    int wave = threadIdx.x >> 6, lane = threadIdx.x & 63;
    int r = blockIdx.x * 4 + wave;
    int n = r & (SEQ - 1);
    const float4* xr = (const float4*)(x + (size_t)r * DIM);
    float4 z = make_float4(0.f, 0.f, 0.f, 0.f);
    float s[8];
#pragma unroll
    for (int i = 0; i < 2; ++i) {
        int c4 = lane * 2 + i;
        float4 v0 = xr[c4];
        float4 vm = (n > 0)       ? xr[c4 - DIM / 4] : z;
        float4 vp = (n < SEQ - 1) ? xr[c4 + DIM / 4] : z;
        s[i * 4 + 0] = v0.x - (vm.x + v0.x + vp.x) * (1.f / 3.f);
        s[i * 4 + 1] = v0.y - (vm.y + v0.y + vp.y) * (1.f / 3.f);
        s[i * 4 + 2] = v0.z - (vm.z + v0.z + vp.z) * (1.f / 3.f);
        s[i * 4 + 3] = v0.w - (vm.w + v0.w + vp.w) * (1.f / 3.f);
    }
    float4* Sr = (float4*)(S + (size_t)r * DIM);
    Sr[lane * 2]     = make_float4(s[0], s[1], s[2], s[3]);
    Sr[lane * 2 + 1] = make_float4(s[4], s[5], s[6], s[7]);

    float sum = 0.f;
#pragma unroll
    for (int j = 0; j < 8; ++j) sum += s[j];
    sum = wave_red(sum);
    float mean = sum * (1.f / DIM);
    float vs = 0.f;
#pragma unroll
    for (int j = 0; j < 8; ++j) { float d = s[j] - mean; vs += d * d; }
    vs = wave_red(vs);
    float rstd = rsqrtf(vs * (1.f / DIM) + 1e-5f);

    int c = lane * 8;
    float4 g0 = ((const float4*)(g + c))[0],  g1v = ((const float4*)(g + c))[1];
    float4 b0 = ((const float4*)(be + c))[0], b1v = ((const float4*)(be + c))[1];
    bf16x8 o;
    o[0] = (bf16)((s[0] - mean) * rstd * g0.x + b0.x);
    o[1] = (bf16)((s[1] - mean) * rstd * g0.y + b0.y);
    o[2] = (bf16)((s[2] - mean) * rstd * g0.z + b0.z);
    o[3] = (bf16)((s[3] - mean) * rstd * g0.w + b0.w);
    o[4] = (bf16)((s[4] - mean) * rstd * g1v.x + b1v.x);
    o[5] = (bf16)((s[5] - mean) * rstd * g1v.y + b1v.y);
    o[6] = (bf16)((s[6] - mean) * rstd * g1v.z + b1v.z);
    o[7] = (bf16)((s[7] - mean) * rstd * g1v.w + b1v.w);
    *(bf16x8*)(XN + (size_t)r * DIM + c) = o;
}

// ---------------- plain LayerNorm (fp32 in -> bf16 out) ----------------
__global__ __launch_bounds__(256) void ln_kernel(const float* __restrict__ X,
                                                 const float* __restrict__ g,
                                                 const float* __restrict__ be,
                                                 bf16* __restrict__ XN)
{
    int wave = threadIdx.x >> 6, lane = threadIdx.x & 63;
    int r = blockIdx.x * 4 + wave;
    const float4* xr = (const float4*)(X + (size_t)r * DIM);
    float4 a0 = xr[lane * 2], a1 = xr[lane * 2 + 1];
    float s[8] = {a0.x, a0.y, a0.z, a0.w, a1.x, a1.y, a1.z, a1.w};
    float sum = 0.f;
#pragma unroll
    for (int j = 0; j < 8; ++j) sum += s[j];
    sum = wave_red(sum);
    float mean = sum * (1.f / DIM);
    float vs = 0.f;
#pragma unroll
    for (int j = 0; j < 8; ++j) { float d = s[j] - mean; vs += d * d; }
    vs = wave_red(vs);
    float rstd = rsqrtf(vs * (1.f / DIM) + 1e-5f);
    int c = lane * 8;
    float4 g0 = ((const float4*)(g + c))[0],  g1v = ((const float4*)(g + c))[1];
    float4 b0 = ((const float4*)(be + c))[0], b1v = ((const float4*)(be + c))[1];
    bf16x8 o;
    o[0] = (bf16)((s[0] - mean) * rstd * g0.x + b0.x);
    o[1] = (bf16)((s[1] - mean) * rstd * g0.y + b0.y);
    o[2] = (bf16)((s[2] - mean) * rstd * g0.z + b0.z);
    o[3] = (bf16)((s[3] - mean) * rstd * g0.w + b0.w);
    o[4] = (bf16)((s[4] - mean) * rstd * g1v.x + b1v.x);
    o[5] = (bf16)((s[5] - mean) * rstd * g1v.y + b1v.y);
    o[6] = (bf16)((s[6] - mean) * rstd * g1v.z + b1v.z);
    o[7] = (bf16)((s[7] - mean) * rstd * g1v.w + b1v.w);
    *(bf16x8*)(XN + (size_t)r * DIM + c) = o;
}

// ---------------- MFMA GEMM: C = A[M,K](bf16) @ Bt[N,K]^T(bf16) + bias, epilogues ----------------
// R5: 256x256 tile, 512 threads = 8 waves (2M x 4N), per-wave 128x64 output.
// Rationale: R4's 64x64 wave tile pays per-phase fixed cost (barrier + lgkm drain +
// wait) every 16 MFMA; measured ~1400cyc/block-phase vs 310cyc MFMA floor. 128x64
// gives 64 MFMA/wave per barrier and cuts ds_reads/MFMA from 0.5 to 0.19.
// Schedule is the R4-verified one: reads-first -> depth-2 prefetch -> MFMA ->
// counted vmcnt(4) -> barrier, triple-buffered.
// LDS [256][32] bf16 (64B rows) + chunk-XOR: read pattern is bank-conflict-free
// (row parity x XOR covers all 32 banks).
enum { M_QKV = 0, M_ATTN = 1, M_FFN1 = 2, M_FFN2 = 3 };

template <int MODE>
__global__ __launch_bounds__(512, 2) void gemm_bt_kernel(const bf16* __restrict__ A, int lda,
                                                         const bf16* __restrict__ Bt,
                                                         const float* __restrict__ bias,
                                                         float* S, const float* __restrict__ X,
                                                         void* Cout, int ldc,
                                                         int N, int K, int rows_per_batch,
                                                         int m_off)
{
    __shared__ __align__(16) bf16 lA[3][256 * 32];   // 48 KB
    __shared__ __align__(16) bf16 lB[3][256 * 32];   // 48 KB  -> 96 KB total, 1 blk/CU
    int tid = threadIdx.x;

    // T1 XCD-chunked swizzle (all grids %8==0 -> bijective)
    int nwg = gridDim.x * gridDim.y;
    int orig = blockIdx.y * gridDim.x + blockIdx.x;
    int wg = (orig & 7) * (nwg >> 3) + (orig >> 3);
    int m0 = (wg / gridDim.x) * 256;
    int n0 = (wg % gridDim.x) * 256;

    const bf16* Abase = A + (size_t)m0 * lda;
    const bf16* Bbase = Bt + (size_t)n0 * K;
    if (rows_per_batch) Bbase += (size_t)(m0 / rows_per_batch) * (size_t)N * K;

    int lane = tid & 63;
    int wave = tid >> 6;            // 0..7
    int wm = (wave >> 2) * 128;     // 2 waves in M
    int wn = (wave & 3) * 64;       // 4 waves in N
    int lm = lane & 15;
    int quad = lane >> 4;
    int ebase = tid & 448;          // wave-uniform part of tid

    floatx4 acc[8][4];
#pragma unroll
    for (int i = 0; i < 8; ++i)
#pragma unroll
        for (int j = 0; j < 4; ++j) acc[i][j] = (floatx4){0.f, 0.f, 0.f, 0.f};

    // stage one 256x32 A-tile + B-tile: 1024 16B-chunks each, 512 threads -> 2+2 loads
    auto stage = [&](int buf, int k0) {
#pragma unroll
        for (int l = 0; l < 2; ++l) {
            int e  = l * 512 + tid;           // chunk id 0..1023
            int eb = l * 512 + ebase;         // wave-uniform dest base
            int row = e >> 2;                 // 0..255
            int col = ((e & 3) ^ (row & 3)) * 8;   // pre-swizzled source chunk
            __builtin_amdgcn_global_load_lds(GLOBAL_AS(Abase + (size_t)row * lda + k0 + col),
                                             LDS_AS(&lA[buf][eb * 8]), 16, 0, 0);
            __builtin_amdgcn_global_load_lds(GLOBAL_AS(Bbase + (size_t)row * K + k0 + col),
                                             LDS_AS(&lB[buf][eb * 8]), 16, 0, 0);
        }
    };

    // prologue: two stages in flight, wait for stage 0 only (4 vmem ops/stage/wave)
    stage(0, 0);
    stage(1, 32);
    asm volatile("s_waitcnt vmcnt(4)" ::: "memory");
    __builtin_amdgcn_s_barrier();

    int nsteps = K >> 5;
    int cur = 0;
    for (int s = 0; s < nsteps; ++s) {
        // 1) LDS reads of the current buffer FIRST (R3 lesson: precede the LDS-writing
        //    gload_lds so the compiler doesn't insert vmcnt(0) to disambiguate)
        bf16x8 af[8], bfv[4];
#pragma unroll
        for (int i = 0; i < 8; ++i) {
            int ra = wm + i * 16 + lm;
            af[i] = *(const bf16x8*)&lA[cur][ra * 32 + (quad ^ (ra & 3)) * 8];
        }
#pragma unroll
        for (int j = 0; j < 4; ++j) {
            int rb = wn + j * 16 + lm;
            bfv[j] = *(const bf16x8*)&lB[cur][rb * 32 + (quad ^ (rb & 3)) * 8];
        }

        // 2) depth-2 prefetch issue (loads fly across the next barrier)
        int kpre = (s + 2) << 5;
        bool issued = kpre < K;
        if (issued) {
            int nxt = cur + 2; if (nxt >= 3) nxt -= 3;
            stage(nxt, kpre);
        }

        // 3) 64 MFMA on registers
#pragma unroll
        for (int i = 0; i < 8; ++i)
#pragma unroll
            for (int j = 0; j < 4; ++j)
                acc[i][j] = __builtin_amdgcn_mfma_f32_16x16x32_bf16(af[i], bfv[j], acc[i][j], 0, 0, 0);

        // 4) counted wait: stage s+1 landed; stage s+2 still in flight
        if (issued) asm volatile("s_waitcnt vmcnt(4)" ::: "memory");
        else        asm volatile("s_waitcnt vmcnt(0)" ::: "memory");
        __builtin_amdgcn_s_barrier();
        cur = (cur == 2) ? 0 : cur + 1;
    }

    // epilogue: C/D layout col = lane&15, row = quad*4 + e (m89-verified)
#pragma unroll
    for (int i = 0; i < 8; ++i) {
        int gm_base = m0 + wm + i * 16 + quad * 4;
#pragma unroll
        for (int j = 0; j < 4; ++j) {
            int gn = n0 + wn + j * 16 + lm;
            float bia = bias[gn];
            if constexpr (MODE == M_FFN2) {
                // out = ffn2 + seasonal(out) + trend(x); share 6 X-rows per 4-row chunk
                int gmg0 = m_off + gm_base;
                int bn = gmg0 & (SEQ - 1);             // chunk base row, mult of 4
                size_t ob = (size_t)gmg0 * DIM + gn;
                const float* Xb = X + ob;
                float xr6[6];
#pragma unroll
                for (int r = 0; r < 6; ++r) {
                    int nr = bn + r - 1;
                    xr6[r] = (nr >= 0 && nr < SEQ) ? Xb[(long)(r - 1) * DIM] : 0.f;
                }
                float* op = (float*)Cout;
#pragma unroll
                for (int e = 0; e < 4; ++e) {
                    size_t o = ob + (size_t)e * DIM;
                    float val = acc[i][j][e] + bia;
                    op[o] = val + op[o] + (xr6[e] + xr6[e + 1] + xr6[e + 2]) * (1.f / 3.f);
                }
            } else {
#pragma unroll
                for (int e = 0; e < 4; ++e) {
                    int gm = gm_base + e;
                    float val = acc[i][j][e] + bia;
                    if constexpr (MODE == M_QKV) {
                        if (gn < 1024) val = (val > 0.f) ? val + 1.f : __expf(val);  // elu+1 on q,k
                        ((bf16*)Cout)[(size_t)gm * ldc + gn] = (bf16)val;
                    } else if constexpr (MODE == M_ATTN) {
                        S[(size_t)gm * DIM + gn] += val;          // seasonal += attn + bo
                    } else {  // M_FFN1
                        val = 0.5f * val * (1.f + erff(val * 0.70710678118654752f));  // exact gelu
                        ((bf16*)Cout)[(size_t)gm * ldc + gn] = (bf16)val;
                    }
                }
            }
        }
    }
}

// ---------------- kv einsum via MFMA: KV[kc][b*8+h][d][f] = sum_{n in kc-chunk} k[n][d]*v[n][f] ----
// One block per (kc,h,b); 256 blocks = 1 block/CU. Same reads-before-stage ordering.
__global__ __launch_bounds__(256) void kv_mfma_kernel(const bf16* __restrict__ QKV,
                                                      float* __restrict__ KV)
{
    int kc = blockIdx.x, h = blockIdx.y, b = blockIdx.z;
    __shared__ __align__(16) bf16 lbuf[3][2 * 128 * 64];   // (lk | lv) x 3, 96 KB
    int tid = threadIdx.x;
    int lane = tid & 63, wave = tid >> 6;
    int lm = lane & 15, quad = lane >> 4;

    floatx4 acc[4][4];
#pragma unroll
    for (int i = 0; i < 4; ++i)
#pragma unroll
        for (int j = 0; j < 4; ++j) acc[i][j] = (floatx4){0.f, 0.f, 0.f, 0.f};

    const bf16* kb = QKV + (size_t)b * SEQ * 1536 + 512 + (size_t)h * 64;
    const bf16* vb = kb + 512;
    int drow = lane >> 3;          // row-within-instruction (8 rows x 128 B = 1 KB)
    int d0 = (lane & 7) * 8;

    auto stage = [&](int buf, int it) {
        int n0 = kc * 1024 + it * 128;
#pragma unroll
        for (int q = 0; q < 4; ++q) {
            int nbase = wave * 32 + q * 8;              // wave-uniform
            int ldsoff = wave * 2048 + q * 512;         // elements (x2B = bytes/2)
            __builtin_amdgcn_global_load_lds(GLOBAL_AS(kb + (size_t)(n0 + nbase + drow) * 1536 + d0),
                                             LDS_AS(&lbuf[buf][ldsoff]), 16, 0, 0);
            __builtin_amdgcn_global_load_lds(GLOBAL_AS(vb + (size_t)(n0 + nbase + drow) * 1536 + d0),
                                             LDS_AS(&lbuf[buf][8192 + ldsoff]), 16, 0, 0);
        }
    };

    stage(0, 0);
    stage(1, 1);
    asm volatile("s_waitcnt vmcnt(8)" ::: "memory");   // stage 0 landed
    __builtin_amdgcn_s_barrier();

    int cur = 0;
    for (int it = 0; it < 8; ++it) {
        // 1) LDS reads first
        const bf16* lk = lbuf[cur];
        const bf16* lv = lbuf[cur] + 8192;
        int nw = wave * 32 + quad * 8;
        bf16x8 af[4], bfv[4];
#pragma unroll
        for (int i = 0; i < 4; ++i) {
            int dd = i * 16 + lm;
#pragma unroll
            for (int j = 0; j < 8; ++j) af[i][j] = lk[(nw + j) * 64 + dd];
#pragma unroll
            for (int j = 0; j < 8; ++j) bfv[i][j] = lv[(nw + j) * 64 + dd];
        }

        // 2) depth-2 prefetch
        bool issued = (it + 2) < 8;
        if (issued) {
            int nxt = cur + 2; if (nxt >= 3) nxt -= 3;
            stage(nxt, it + 2);
        }

        // 3) MFMA
#pragma unroll
        for (int i = 0; i < 4; ++i)
#pragma unroll
            for (int j = 0; j < 4; ++j)
                acc[i][j] = __builtin_amdgcn_mfma_f32_16x16x32_bf16(af[i], bfv[j], acc[i][j], 0, 0, 0);

        // 4) counted wait (8 vmem ops per stage per wave)
        if (issued) asm volatile("s_waitcnt vmcnt(8)" ::: "memory");
        else        asm volatile("s_waitcnt vmcnt(0)" ::: "memory");
        __builtin_amdgcn_s_barrier();
        cur = (cur == 2) ? 0 : cur + 1;
    }

    // cross-wave reduce in LDS (reuse lbuf as 2 x 16 KB fp32), then store KV partial
    __syncthreads();
    float* red = (float*)lbuf;
    if (wave < 2) {
#pragma unroll
        for (int i = 0; i < 4; ++i)
#pragma unroll
            for (int j = 0; j < 4; ++j)
#pragma unroll
                for (int e = 0; e < 4; ++e)
                    red[wave * 4096 + (i * 16 + quad * 4 + e) * 64 + j * 16 + lm] = acc[i][j][e];
    }
    __syncthreads();
    if (wave >= 2) {
#pragma unroll
        for (int i = 0; i < 4; ++i)
#pragma unroll
            for (int j = 0; j < 4; ++j)
#pragma unroll
                for (int e = 0; e < 4; ++e)
                    red[(wave - 2) * 4096 + (i * 16 + quad * 4 + e) * 64 + j * 16 + lm] += acc[i][j][e];
    }
    __syncthreads();
    float* dst = KV + ((size_t)kc * 64 + b * 8 + h) * 4096;
#pragma unroll
    for (int p = 0; p < 4; ++p) {
        int e4 = (tid + p * 256) * 4;
        float4 a = *(const float4*)&red[e4];
        float4 c4 = *(const float4*)&red[4096 + e4];
        a.x += c4.x; a.y += c4.y; a.z += c4.z; a.w += c4.w;
        *(float4*)&dst[e4] = a;
    }
}

// ---------------- fold Wo (reduce 4 kc-partials): KVWT[b][j][h*64+d] ----------------
// 512 blocks = 64 (b,h) x 8 j-chunks; skv staged transposed so inner reads are b128 broadcasts.
__global__ __launch_bounds__(256) void kvw_kernel(const float* __restrict__ KV,
                                                  const float* __restrict__ Wo,
                                                  bf16* __restrict__ KVWT)
{
    int jc = blockIdx.x & 7, bh = blockIdx.x >> 3;
    int h = bh & 7, b = bh >> 3;
    __shared__ float skvT[64 * 68];   // [f][d], pad 4 keeps 16B align, 17.4 KB
    int tid = threadIdx.x;
    const float* src = KV + (size_t)bh * 4096;
#pragma unroll
    for (int p = 0; p < 16; ++p) {
        int e = tid + p * 256;
        float s = src[e] + src[e + 262144] + src[e + 524288] + src[e + 786432];
        skvT[(e & 63) * 68 + (e >> 6)] = s;     // transpose: skvT[f][d] = kv[d][f]
    }
    __syncthreads();

    int j = tid & 63, dq = tid >> 6;   // dq == wave index -> wave-uniform
    int j0 = jc * 64;
    floatx4 acc4[4];
#pragma unroll
    for (int c = 0; c < 4; ++c) acc4[c] = (floatx4){0.f, 0.f, 0.f, 0.f};
    const float* wop = Wo + (size_t)h * 64 * 512 + j0 + j;
#pragma unroll 8
    for (int f = 0; f < 64; ++f) {
        float w = wop[(size_t)f * 512];           // coalesced across lanes
        const float* sp = &skvT[f * 68 + dq * 16];
#pragma unroll
        for (int c = 0; c < 4; ++c) {
            floatx4 s = *(const floatx4*)(sp + c * 4);   // wave-uniform b128 broadcast
            acc4[c] += s * w;
        }
    }
    bf16* dst = KVWT + (size_t)b * 262144 + (size_t)(j0 + j) * 512 + h * 64 + dq * 16;
    bf16x8 o0, o1;
#pragma unroll
    for (int t = 0; t < 8; ++t) { o0[t] = (bf16)acc4[t >> 2][t & 3]; o1[t] = (bf16)acc4[2 + (t >> 2)][t & 3]; }
    *(bf16x8*)dst = o0;
    *(bf16x8*)(dst + 8) = o1;
}

// ---------------- launch ----------------
extern "C" void kernel_launch(void* const* d_in, const int* in_sizes, int n_in,
                              void* d_out, int out_size, void* d_ws, size_t ws_size,
                              hipStream_t stream)
{
    const float* x   = (const float*)d_in[0];
    const float* Wq  = (const float*)d_in[1];
    const float* bq  = (const float*)d_in[2];
    const float* Wk  = (const float*)d_in[3];
    const float* bk  = (const float*)d_in[4];
    const float* Wv  = (const float*)d_in[5];
    const float* bv  = (const float*)d_in[6];
    const float* Wo  = (const float*)d_in[7];
    const float* bo  = (const float*)d_in[8];
    const float* g1  = (const float*)d_in[9];
    const float* b1  = (const float*)d_in[10];
    const float* g2  = (const float*)d_in[11];
    const float* b2  = (const float*)d_in[12];
    const float* Wf1 = (const float*)d_in[13];
    const float* bf1 = (const float*)d_in[14];
    const float* Wf2 = (const float*)d_in[15];
    const float* bf2 = (const float*)d_in[16];
    float* out = (float*)d_out;      // also holds seasonal residual S (fp32)
    (void)in_sizes; (void)n_in; (void)out_size;

    char* ws = (char*)d_ws;
    size_t off = 0;
    auto alloc = [&](size_t bytes) -> char* {
        char* p = ws + off;
        off += (bytes + 255) & ~(size_t)255;
        return p;
    };
    bf16*  WqkvT = (bf16*)alloc((size_t)1536 * 512 * 2);
    float* bias3 = (float*)alloc(1536 * 4);
    bf16*  Wf1T  = (bf16*)alloc((size_t)2048 * 512 * 2);
    bf16*  Wf2T  = (bf16*)alloc((size_t)512 * 2048 * 2);
    size_t post_xn_off = 0;          // offset of first buffer dead by FFN time
    bf16*  XN    = (bf16*)alloc((size_t)ROWS * DIM * 2);
    post_xn_off = off;
    float* KV    = (float*)alloc((size_t)4 * 64 * 4096 * 4);  // 4 kc-partials
    bf16*  KVWT  = (bf16*)alloc((size_t)8 * 512 * 512 * 2);
    bf16*  QKV   = (bf16*)alloc((size_t)ROWS * 1536 * 2);

    // Merged-FFN path: full H1 [32768 x 2048] bf16 (134.2 MB) overlaid on
    // KV|KVWT|QKV (all dead once the ATTN gemm completed). Gate on ws_size.
    size_t h1_bytes  = (size_t)ROWS * DFF * 2;
    bool   merged    = ws_size >= post_xn_off + h1_bytes;
    bf16*  H1full    = (bf16*)(ws + post_xn_off);
    bf16*  H1chunk   = QKV;          // chunked fallback: aliases QKV (dead after attn)

    prep_w3_kernel<<<3072, 256, 0, stream>>>(Wq, Wk, Wv, WqkvT);
    prep_w_kernel<<<4096, 256, 0, stream>>>(Wf1, Wf1T, 512, 2048);
    prep_w_kernel<<<4096, 256, 0, stream>>>(Wf2, Wf2T, 2048, 512);
    pack_bias_kernel<<<6, 256, 0, stream>>>(bq, bk, bv, bias3);

    decomp_ln_kernel<<<8192, 256, 0, stream>>>(x, g1, b1, out, XN);

    gemm_bt_kernel<M_QKV><<<dim3(6, 128), 512, 0, stream>>>(
        XN, 512, WqkvT, bias3, nullptr, nullptr, QKV, 1536, 1536, 512, 0, 0);

    kv_mfma_kernel<<<dim3(4, 8, 8), 256, 0, stream>>>(QKV, KV);

    kvw_kernel<<<512, 256, 0, stream>>>(KV, Wo, KVWT);

    gemm_bt_kernel<M_ATTN><<<dim3(2, 128), 512, 0, stream>>>(
        QKV, 1536, KVWT, bo, out, nullptr, nullptr, 0, 512, 512, 4096, 0);

    ln_kernel<<<8192, 256, 0, stream>>>(out, g2, b2, XN);

    if (merged) {
        gemm_bt_kernel<M_FFN1><<<dim3(8, 128), 512, 0, stream>>>(
            XN, 512, Wf1T, bf1, nullptr, nullptr, H1full, 2048, 2048, 512, 0, 0);
        gemm_bt_kernel<M_FFN2><<<dim3(2, 128), 512, 0, stream>>>(
            H1full, 2048, Wf2T, bf2, nullptr, x, out, 512, 512, 2048, 0, 0);
    } else {
        for (int c = 0; c < 2; ++c) {
            gemm_bt_kernel<M_FFN1><<<dim3(8, 64), 512, 0, stream>>>(
                XN + (size_t)c * 16384 * 512, 512, Wf1T, bf1, nullptr, nullptr,
                H1chunk, 2048, 2048, 512, 0, 0);
            gemm_bt_kernel<M_FFN2><<<dim3(2, 64), 512, 0, stream>>>(
                H1chunk, 2048, Wf2T, bf2, nullptr, x, out, 512, 512, 2048, 0, c * 16384);
        }
    }
}